// Round 6
// baseline (220.337 us; speedup 1.0000x reference)
//
#include <hip/hip_runtime.h>

// VQ nearest-embedding, fused split-fp16 MFMA, double-buffered LDS.
// argmin_k ||x-e_k||^2 == argmin_k (0.5*||e_k||^2 - x.e_k).
// x = xh+xl, e = eh+el (fp16 RNE splits); 3 MFMA terms (hh, hl, lh).
// R10: CD=32 (64 barriers) + quad-packed epk. 152us. Diagnosis: LDS pipe
//      ~3450 of 5700 cyc/chunk; reads set by wave-sharing geometry
//      (16 waves x 12 reads), conflicts from the 20-bank row stride.
// R11: cut the LDS pipe two ways (template/sync structure unchanged):
//   - 512 thr, 8 waves as 2m x 4n groups, each wave 2m x 2n tiles (R5's
//     verified map): B panels read by 2 m-groups instead of 4
//     -> 128 reads/chunk (-33%). launch_bounds(512,2) -> 256 VGPR cap,
//     no R8-style spills.
//   - LDA 40 -> 32 (64B rows = CD) + XOR slot swizzle
//     slot' = slot ^ ((row>>1)&3) on BOTH ds_write and ds_read sides
//     (all reg-staged, so legal): reads and writes cover all 8
//     16B-bank-groups uniformly -> ~0 conflicts; all LDS stores b128;
//     LDS 127 -> 96 KB.
//   Fragment bits + MFMA order identical to R5/R10 -> absmax 0.

typedef __attribute__((ext_vector_type(8))) _Float16 half8v;  // 8 fp16 = 4 VGPRs
typedef __attribute__((ext_vector_type(16))) float floatx16;  // 32x32 acc
typedef unsigned int uint;
typedef unsigned short ushort;

#define DD 256
#define KK 2048
#define SS 1024
#define NN 32768
#define MT 128      // latents per block
#define NTT 256     // codes per kt tile (8 tiles cover K=2048)
#define CD 32       // chunk K-depth (halfs)
#define LDB 32      // LDS row stride in fp16 elems (64 B, dense = CD)
#define MFMA_F16 __builtin_amdgcn_mfma_f32_32x32x16_f16

union HU { _Float16 f; ushort u; };

__device__ __forceinline__ void split16(float v, ushort& h, ushort& l) {
    HU a, b;
    a.f = (_Float16)v;                       // RNE
    b.f = (_Float16)(v - (float)a.f);
    h = a.u; l = b.u;
}

__device__ __forceinline__ uint pk(ushort a, ushort b) {
    return (uint)a | ((uint)b << 16);
}

// swizzled ushort index of the 16B slot `slot` (0..3) in row `row`.
// XOR of (row>>1)&3 spreads the 4 slots x row-parity over all 8
// 16B-bank-groups for both the (row=lane) read pattern and the
// (row=lane, slot fixed) write pattern -> conflict-free b128.
__device__ __forceinline__ int swz(int row, int slot) {
    return row * LDB + ((slot ^ ((row >> 1) & 3)) << 3);
}

// 64 blocks: block b covers codes [b*32, b*32+32); 8 threads/code sum 32 d's.
__global__ __launch_bounds__(256) void hn_kernel(const float* __restrict__ emb,
                                                 float* __restrict__ hn) {
    __shared__ float red[256];
    const int tid = threadIdx.x;
    const int k = blockIdx.x * 32 + (tid & 31);
    const int j = tid >> 5;              // 0..7: d-chunk
    float a = 0.f;
#pragma unroll
    for (int i = 0; i < 32; ++i) {
        float e = emb[(size_t)(j * 32 + i) * KK + k];
        a += e * e;
    }
    red[tid] = a;
    __syncthreads();
    if (j == 0) {
        float s = a;
#pragma unroll
        for (int g = 1; g < 8; ++g) s += red[g * 32 + (tid & 31)];
        hn[k] = 0.5f * s;
    }
}

// emb (d,k) f32 -> epk quad-interleaved uint4 planes:
//   uint4 index (q*2 + p)*KK + k holds, for plane p in {h,l}, code k,
//   packed d-pairs of quad q (element j = pack(d=8q+2j, d=8q+2j+1)).
__global__ __launch_bounds__(256) void pack_emb(const float* __restrict__ emb,
                                                uint4* __restrict__ epk) {
    int idx = blockIdx.x * 256 + threadIdx.x;     // 65536 = 32 quads * 2048 k
    int k = idx & (KK - 1);
    int q = idx >> 11;                            // d-quad: d = 8q..8q+7
    ushort h[8], l[8];
#pragma unroll
    for (int j = 0; j < 8; ++j) {
        float e = emb[(size_t)(8 * q + j) * KK + k];
        split16(e, h[j], l[j]);
    }
    uint4 H, L;
    H.x = pk(h[0], h[1]); H.y = pk(h[2], h[3]);
    H.z = pk(h[4], h[5]); H.w = pk(h[6], h[7]);
    L.x = pk(l[0], l[1]); L.y = pk(l[2], l[3]);
    L.z = pk(l[4], l[5]); L.w = pk(l[6], l[7]);
    epk[(size_t)(q * 2 + 0) * KK + k] = H;
    epk[(size_t)(q * 2 + 1) * KK + k] = L;
}

// PRE: B from quad-packed epk (dwordx4). !PRE: B from emb f32 + in-loop split.
template <bool PRE>
__global__ __launch_bounds__(512, 2) void vq_fused(
        const float* __restrict__ x, const float* __restrict__ emb,
        const float* __restrict__ hn, const uint4* __restrict__ epk,
        float* __restrict__ out) {
    __shared__ ushort Ah[2][MT * LDB], Al[2][MT * LDB];     // 8 KB each plane/buf
    __shared__ ushort Bh[2][NTT * LDB], Bl[2][NTT * LDB];   // 16 KB each plane/buf
    __shared__ float sv[4][MT];
    __shared__ int   sc[4][MT];
    __shared__ int   bc[MT];

    const int tid = threadIdx.x;
    const int lane = tid & 63;
    const int wid = tid >> 6;          // 8 waves: 2(m) x 4(n)
    const int colk = lane & 31;
    const int half = lane >> 5;
    const int wm = (wid & 1) * 64;     // wave covers m-tiles wm, wm+32
    const int wn = (wid >> 1) * 64;    // and n-tiles wn, wn+32

    const int base_n = blockIdx.x * MT;
    const int bq = base_n >> 10;          // batch (SS = 1024)
    const int sb = base_n & (SS - 1);     // spatial base

    // staging assignment (512 threads)
    // A: thread covers latent lat_a, d-octet qa (d = dt + 8*qa + 0..7).
    const int lat_a = tid & 127;
    const int qa = tid >> 7;              // 0..3
    // B(PRE): thread covers code cod_b, plane pB, all 4 slots.
    // B(!PRE): thread covers code cod_b, half-range oB, both planes.
    const int cod_b = tid & 255;
    const int pB = tid >> 8;              // 0..1
    const int oB = tid >> 8;              // 0..1

    const float* xA = x + (size_t)bq * DD * SS + sb + lat_a;

    floatx16 acc[2][2];
#pragma unroll
    for (int i = 0; i < 2; ++i)
#pragma unroll
        for (int j = 0; j < 2; ++j) acc[i][j] = (floatx16)(0.0f);

    float bestv[2][16];
    int bestc[2][16];
#pragma unroll
    for (int t = 0; t < 2; ++t)
#pragma unroll
        for (int r = 0; r < 16; ++r) { bestv[t][r] = 3.4e38f; bestc[t][r] = 0; }

    float fa[8];
    uint4 uq[4];           // PRE: 4 slots of this thread's plane
    float fb[16];          // !PRE raw f32

    // ---- prefetch chunk 0 (kt=0, dt=0) ----
#pragma unroll
    for (int j = 0; j < 8; ++j) fa[j] = xA[(size_t)(8 * qa + j) * SS];
    if constexpr (PRE) {
#pragma unroll
        for (int s = 0; s < 4; ++s)
            uq[s] = epk[(size_t)(s * 2 + pB) * KK + cod_b];
    } else {
#pragma unroll
        for (int i = 0; i < 16; ++i)
            fb[i] = emb[(size_t)(oB * 16 + i) * KK + cod_b];
    }
    // ---- stage chunk 0 -> buffer 0 ----
    {
        ushort h[8], l[8];
#pragma unroll
        for (int j = 0; j < 8; ++j) split16(fa[j], h[j], l[j]);
        uint4 H, L;
        H.x = pk(h[0], h[1]); H.y = pk(h[2], h[3]);
        H.z = pk(h[4], h[5]); H.w = pk(h[6], h[7]);
        L.x = pk(l[0], l[1]); L.y = pk(l[2], l[3]);
        L.z = pk(l[4], l[5]); L.w = pk(l[6], l[7]);
        *reinterpret_cast<uint4*>(&Ah[0][swz(lat_a, qa)]) = H;
        *reinterpret_cast<uint4*>(&Al[0][swz(lat_a, qa)]) = L;
        if constexpr (PRE) {
            ushort* Bp = pB ? &Bl[0][0] : &Bh[0][0];
#pragma unroll
            for (int s = 0; s < 4; ++s)
                *reinterpret_cast<uint4*>(&Bp[swz(cod_b, s)]) = uq[s];
        } else {
            ushort hh[16], ll[16];
#pragma unroll
            for (int i = 0; i < 16; ++i) split16(fb[i], hh[i], ll[i]);
            uint4 w;
            w.x = pk(hh[0], hh[1]);  w.y = pk(hh[2], hh[3]);
            w.z = pk(hh[4], hh[5]);  w.w = pk(hh[6], hh[7]);
            *reinterpret_cast<uint4*>(&Bh[0][swz(cod_b, oB * 2)]) = w;
            w.x = pk(hh[8], hh[9]);  w.y = pk(hh[10], hh[11]);
            w.z = pk(hh[12], hh[13]); w.w = pk(hh[14], hh[15]);
            *reinterpret_cast<uint4*>(&Bh[0][swz(cod_b, oB * 2 + 1)]) = w;
            w.x = pk(ll[0], ll[1]);  w.y = pk(ll[2], ll[3]);
            w.z = pk(ll[4], ll[5]);  w.w = pk(ll[6], ll[7]);
            *reinterpret_cast<uint4*>(&Bl[0][swz(cod_b, oB * 2)]) = w;
            w.x = pk(ll[8], ll[9]);  w.y = pk(ll[10], ll[11]);
            w.z = pk(ll[12], ll[13]); w.w = pk(ll[14], ll[15]);
            *reinterpret_cast<uint4*>(&Bl[0][swz(cod_b, oB * 2 + 1)]) = w;
        }
    }
    __syncthreads();

    for (int c = 0; c < 64; ++c) {           // 8 kt x 8 dt chunks of K-depth 32
        const int cur = c & 1, nxt = cur ^ 1;
        // ---- prefetch next chunk's globals (in flight during MFMA) ----
        if (c < 63) {
            const int c1 = c + 1;
            const int kt1 = c1 >> 3;
            const int dt1 = (c1 & 7) * CD;
#pragma unroll
            for (int j = 0; j < 8; ++j)
                fa[j] = xA[(size_t)(dt1 + 8 * qa + j) * SS];
            if constexpr (PRE) {
                const int qg = dt1 >> 3;
                const size_t kb = (size_t)kt1 * NTT + cod_b;
#pragma unroll
                for (int s = 0; s < 4; ++s)
                    uq[s] = epk[(size_t)((qg + s) * 2 + pB) * KK + kb];
            } else {
#pragma unroll
                for (int i = 0; i < 16; ++i)
                    fb[i] = emb[(size_t)(dt1 + oB * 16 + i) * KK
                                + kt1 * NTT + cod_b];
            }
        }
        // ---- fragments from current buffer + 2 k-substeps x 12 MFMA ----
#pragma unroll
        for (int t = 0; t < 2; ++t) {
            const int sA = t * 2 + half;
            half8v ah0 = *reinterpret_cast<const half8v*>(&Ah[cur][swz(wm + colk, sA)]);
            half8v ah1 = *reinterpret_cast<const half8v*>(&Ah[cur][swz(wm + 32 + colk, sA)]);
            half8v al0 = *reinterpret_cast<const half8v*>(&Al[cur][swz(wm + colk, sA)]);
            half8v al1 = *reinterpret_cast<const half8v*>(&Al[cur][swz(wm + 32 + colk, sA)]);
            half8v bh0 = *reinterpret_cast<const half8v*>(&Bh[cur][swz(wn + colk, sA)]);
            half8v bh1 = *reinterpret_cast<const half8v*>(&Bh[cur][swz(wn + 32 + colk, sA)]);
            half8v bl0 = *reinterpret_cast<const half8v*>(&Bl[cur][swz(wn + colk, sA)]);
            half8v bl1 = *reinterpret_cast<const half8v*>(&Bl[cur][swz(wn + 32 + colk, sA)]);

            acc[0][0] = MFMA_F16(ah0, bh0, acc[0][0], 0, 0, 0);
            acc[0][0] = MFMA_F16(ah0, bl0, acc[0][0], 0, 0, 0);
            acc[0][0] = MFMA_F16(al0, bh0, acc[0][0], 0, 0, 0);

            acc[0][1] = MFMA_F16(ah0, bh1, acc[0][1], 0, 0, 0);
            acc[0][1] = MFMA_F16(ah0, bl1, acc[0][1], 0, 0, 0);
            acc[0][1] = MFMA_F16(al0, bh1, acc[0][1], 0, 0, 0);

            acc[1][0] = MFMA_F16(ah1, bh0, acc[1][0], 0, 0, 0);
            acc[1][0] = MFMA_F16(ah1, bl0, acc[1][0], 0, 0, 0);
            acc[1][0] = MFMA_F16(al1, bh0, acc[1][0], 0, 0, 0);

            acc[1][1] = MFMA_F16(ah1, bh1, acc[1][1], 0, 0, 0);
            acc[1][1] = MFMA_F16(ah1, bl1, acc[1][1], 0, 0, 0);
            acc[1][1] = MFMA_F16(al1, bh1, acc[1][1], 0, 0, 0);
        }

        // ---- stage prefetched -> NEXT buffer (overlaps MFMA) ----
        if (c < 63) {
            ushort h[8], l[8];
#pragma unroll
            for (int j = 0; j < 8; ++j) split16(fa[j], h[j], l[j]);
            uint4 H, L;
            H.x = pk(h[0], h[1]); H.y = pk(h[2], h[3]);
            H.z = pk(h[4], h[5]); H.w = pk(h[6], h[7]);
            L.x = pk(l[0], l[1]); L.y = pk(l[2], l[3]);
            L.z = pk(l[4], l[5]); L.w = pk(l[6], l[7]);
            *reinterpret_cast<uint4*>(&Ah[nxt][swz(lat_a, qa)]) = H;
            *reinterpret_cast<uint4*>(&Al[nxt][swz(lat_a, qa)]) = L;
            if constexpr (PRE) {
                ushort* Bp = pB ? &Bl[nxt][0] : &Bh[nxt][0];
#pragma unroll
                for (int s = 0; s < 4; ++s)
                    *reinterpret_cast<uint4*>(&Bp[swz(cod_b, s)]) = uq[s];
            } else {
                ushort hh[16], ll[16];
#pragma unroll
                for (int i = 0; i < 16; ++i) split16(fb[i], hh[i], ll[i]);
                uint4 w;
                w.x = pk(hh[0], hh[1]);  w.y = pk(hh[2], hh[3]);
                w.z = pk(hh[4], hh[5]);  w.w = pk(hh[6], hh[7]);
                *reinterpret_cast<uint4*>(&Bh[nxt][swz(cod_b, oB * 2)]) = w;
                w.x = pk(hh[8], hh[9]);  w.y = pk(hh[10], hh[11]);
                w.z = pk(hh[12], hh[13]); w.w = pk(hh[14], hh[15]);
                *reinterpret_cast<uint4*>(&Bh[nxt][swz(cod_b, oB * 2 + 1)]) = w;
                w.x = pk(ll[0], ll[1]);  w.y = pk(ll[2], ll[3]);
                w.z = pk(ll[4], ll[5]);  w.w = pk(ll[6], ll[7]);
                *reinterpret_cast<uint4*>(&Bl[nxt][swz(cod_b, oB * 2)]) = w;
                w.x = pk(ll[8], ll[9]);  w.y = pk(ll[10], ll[11]);
                w.z = pk(ll[12], ll[13]); w.w = pk(ll[14], ll[15]);
                *reinterpret_cast<uint4*>(&Bl[nxt][swz(cod_b, oB * 2 + 1)]) = w;
            }
        }
        // ---- per-kt epilogue: scores -> running per-lane argmin, reset acc ----
        if ((c & 7) == 7) {
            const int kt = c >> 3;
            const int cd0 = kt * NTT + wn + colk;
            const int cd1 = cd0 + 32;
            const float h0 = hn[cd0];
            const float h1 = hn[cd1];
#pragma unroll
            for (int tm = 0; tm < 2; ++tm) {
#pragma unroll
                for (int r = 0; r < 16; ++r) {
                    float s0 = h0 - acc[tm][0][r];
                    float s1 = h1 - acc[tm][1][r];
                    float v = s0; int cd = cd0;
                    if (s1 < s0) { v = s1; cd = cd1; }   // strict <: smaller code wins ties
                    if (v < bestv[tm][r]) { bestv[tm][r] = v; bestc[tm][r] = cd; }
                    acc[tm][0][r] = 0.f;
                    acc[tm][1][r] = 0.f;
                }
            }
        }
        __syncthreads();   // single barrier per chunk (dbuf)
    }

    // ---- cross-lane argmin: butterfly over the 32 colk lanes ----
#pragma unroll
    for (int tm = 0; tm < 2; ++tm) {
#pragma unroll
        for (int r = 0; r < 16; ++r) {
            float v = bestv[tm][r];
            int cd = bestc[tm][r];
#pragma unroll
            for (int mk = 1; mk < 32; mk <<= 1) {
                float ov = __shfl_xor(v, mk);
                int oc = __shfl_xor(cd, mk);
                if (ov < v || (ov == v && oc < cd)) { v = ov; cd = oc; }
            }
            if (colk == 0) {
                const int row = (r & 3) + 8 * (r >> 2) + 4 * half;  // verified C/D map
                sv[wid >> 1][wm + tm * 32 + row] = v;
                sc[wid >> 1][wm + tm * 32 + row] = cd;
            }
        }
    }
    __syncthreads();
    // ---- combine the 4 n-wave groups ----
    if (tid < MT) {
        float v = sv[0][tid]; int cd = sc[0][tid];
#pragma unroll
        for (int g = 1; g < 4; ++g) {
            float ov = sv[g][tid]; int oc = sc[g][tid];
            if (ov < v || (ov == v && oc < cd)) { v = ov; cd = oc; }
        }
        bc[tid] = cd;
    }
    __syncthreads();
    // ---- fused gather: out[(bq*DD+d)*SS + sb + m] = emb[d*KK + bc[m]] ----
    {
        const int mq = tid & 31;     // float4 group along m (128 cols = 32 groups)
        const int dg = tid >> 5;     // 0..15, 16 d's each
        const int k0 = bc[mq * 4 + 0];
        const int k1 = bc[mq * 4 + 1];
        const int k2 = bc[mq * 4 + 2];
        const int k3 = bc[mq * 4 + 3];
#pragma unroll 4
        for (int dd = 0; dd < 16; ++dd) {
            const int d = dg * 16 + dd;
            const float* er = emb + (size_t)d * KK;
            float4 o = make_float4(er[k0], er[k1], er[k2], er[k3]);
            reinterpret_cast<float4*>(&out[((size_t)bq * DD + d) * SS + sb])[mq] = o;
        }
    }
}

extern "C" void kernel_launch(void* const* d_in, const int* in_sizes, int n_in,
                              void* d_out, int out_size, void* d_ws, size_t ws_size,
                              hipStream_t stream) {
    const float* x = (const float*)d_in[0];     // (32,256,32,32)
    const float* emb = (const float*)d_in[1];   // (256,2048)
    float* out = (float*)d_out;
    float* hn = (float*)d_ws;                   // 2048 f32 = 8 KB (proven safe)
    uint4* epk = (uint4*)((char*)d_ws + KK * sizeof(float));  // 2 MB packed emb

    // 32 quads * 2 planes * 2048 codes * 16 B = 2 MB
    const size_t need = (size_t)KK * 4 + (size_t)32 * 2 * KK * 16;

    hipLaunchKernelGGL(hn_kernel, dim3(KK / 32), dim3(256), 0, stream, emb, hn);
    if (ws_size >= need) {
        hipLaunchKernelGGL(pack_emb, dim3(65536 / 256), dim3(256), 0, stream,
                           emb, epk);
        hipLaunchKernelGGL((vq_fused<true>), dim3(NN / MT), dim3(512), 0, stream,
                           x, emb, hn, epk, out);
    } else {
        hipLaunchKernelGGL((vq_fused<false>), dim3(NN / MT), dim3(512), 0, stream,
                           x, emb, hn, epk, out);
    }
}

// Round 7
// 211.543 us; speedup vs baseline: 1.0416x; 1.0416x over previous
//
#include <hip/hip_runtime.h>

// VQ nearest-embedding, fused split-fp16 MFMA, double-buffered LDS.
// argmin_k ||x-e_k||^2 == argmin_k (0.5*||e_k||^2 - x.e_k).
// x = xh+xl, e = eh+el (fp16 RNE splits); 3 MFMA terms (hh, hl, lh).
// R10 (best, 152us): 1024 thr, 16 waves 4m x 4n, CD=32, LDA=40, quad epk.
// R11: 512-thr low-traffic variant was neutral (TLP loss ate the gain).
// R12: back to R10 + PREFETCH DISTANCE 2. R10's chunk ended with all 16
//      waves phase-locked in a vmcnt stall: loads issued at chunk top,
//      consumed at chunk bottom (~500cyc gap < ~900cyc HBM latency).
//      Now: issue loads(c+2) -> pack+write data(c+1) (issued a FULL chunk
//      ago, vmcnt wait ~0) -> compute(c) (no global dep) -> barrier.
//      Two named register sets, even/odd steps explicitly unrolled
//      (static indexing; loads legally stay in flight across s_barrier
//      since destinations are private VGPRs).
//      LDS layout, fragment bits, accumulation order identical to R10
//      -> bit-identical scores, absmax 0.

typedef __attribute__((ext_vector_type(8))) _Float16 half8v;  // 8 fp16 = 4 VGPRs
typedef __attribute__((ext_vector_type(16))) float floatx16;  // 32x32 acc
typedef unsigned int uint;
typedef unsigned short ushort;

#define DD 256
#define KK 2048
#define SS 1024
#define NN 32768
#define MT 128      // latents per block
#define NTT 256     // codes per kt tile (8 tiles cover K=2048)
#define CD 32       // chunk K-depth (halfs)
#define LDA 40      // LDS row stride in fp16 elems (80 B: 16B-aligned)
#define MFMA_F16 __builtin_amdgcn_mfma_f32_32x32x16_f16

union HU { _Float16 f; ushort u; };

__device__ __forceinline__ void split16(float v, ushort& h, ushort& l) {
    HU a, b;
    a.f = (_Float16)v;                       // RNE
    b.f = (_Float16)(v - (float)a.f);
    h = a.u; l = b.u;
}

__device__ __forceinline__ uint pk(ushort a, ushort b) {
    return (uint)a | ((uint)b << 16);
}

// 64 blocks: block b covers codes [b*32, b*32+32); 8 threads/code sum 32 d's.
__global__ __launch_bounds__(256) void hn_kernel(const float* __restrict__ emb,
                                                 float* __restrict__ hn) {
    __shared__ float red[256];
    const int tid = threadIdx.x;
    const int k = blockIdx.x * 32 + (tid & 31);
    const int j = tid >> 5;              // 0..7: d-chunk
    float a = 0.f;
#pragma unroll
    for (int i = 0; i < 32; ++i) {
        float e = emb[(size_t)(j * 32 + i) * KK + k];
        a += e * e;
    }
    red[tid] = a;
    __syncthreads();
    if (j == 0) {
        float s = a;
#pragma unroll
        for (int g = 1; g < 8; ++g) s += red[g * 32 + (tid & 31)];
        hn[k] = 0.5f * s;
    }
}

// emb (d,k) f32 -> epk quad-interleaved uint4 planes:
//   uint4 index (q*2 + p)*KK + k   holds, for plane p in {h,l}, code k,
//   packed d-pairs of quad q (element j = pack(d=8q+2j, d=8q+2j+1)).
__global__ __launch_bounds__(256) void pack_emb(const float* __restrict__ emb,
                                                uint4* __restrict__ epk) {
    int idx = blockIdx.x * 256 + threadIdx.x;     // 65536 = 32 quads * 2048 k
    int k = idx & (KK - 1);
    int q = idx >> 11;                            // d-quad: d = 8q..8q+7
    ushort h[8], l[8];
#pragma unroll
    for (int j = 0; j < 8; ++j) {
        float e = emb[(size_t)(8 * q + j) * KK + k];
        split16(e, h[j], l[j]);
    }
    uint4 H, L;
    H.x = pk(h[0], h[1]); H.y = pk(h[2], h[3]);
    H.z = pk(h[4], h[5]); H.w = pk(h[6], h[7]);
    L.x = pk(l[0], l[1]); L.y = pk(l[2], l[3]);
    L.z = pk(l[4], l[5]); L.w = pk(l[6], l[7]);
    epk[(size_t)(q * 2 + 0) * KK + k] = H;
    epk[(size_t)(q * 2 + 1) * KK + k] = L;
}

// PRE: B from quad-packed epk (dwordx4). !PRE: B from emb f32 + in-loop split.
template <bool PRE>
__global__ __launch_bounds__(1024, 4) void vq_fused(
        const float* __restrict__ x, const float* __restrict__ emb,
        const float* __restrict__ hn, const uint4* __restrict__ epk,
        float* __restrict__ out) {
    __shared__ ushort Ah[2][MT * LDA], Al[2][MT * LDA];     // 10 KB each plane/buf
    __shared__ ushort Bh[2][NTT * LDA], Bl[2][NTT * LDA];   // 20 KB each plane/buf
    __shared__ float sv[4][MT];
    __shared__ int   sc[4][MT];
    __shared__ int   bc[MT];

    const int tid = threadIdx.x;
    const int lane = tid & 63;
    const int wid = tid >> 6;          // 16 waves: 4(m) x 4(n)
    const int colk = lane & 31;
    const int half = lane >> 5;
    const int wm = (wid & 3) * 32;     // 4 m-tiles of 32 cover MT=128
    const int wn = (wid >> 2) * 64;    // 4 n-groups of 64 (2 tiles each)

    const int base_n = blockIdx.x * MT;
    const int bq = base_n >> 10;          // batch (SS = 1024)
    const int sb = base_n & (SS - 1);     // spatial base

    // staging assignment (1024 threads) — R10's maps
    const int lat_a = tid & 127;          // A: one latent
    const int d2a = tid >> 7;             // 0..7: d-pair within half-chunk
    const int cod_b = tid & 255;          // B: one code
    const int pB = (tid >> 8) & 1;        // 0=h, 1=l
    const int oB = tid >> 9;              // 0..1: quad-pair within chunk

    const float* xA = x + ((size_t)bq * DD + 2 * d2a) * SS + sb + lat_a;

    floatx16 acc[2];                      // 2 n-tiles (wn, wn+32)
#pragma unroll
    for (int j = 0; j < 2; ++j) acc[j] = (floatx16)(0.0f);

    float bestv[16];
    int bestc[16];
#pragma unroll
    for (int r = 0; r < 16; ++r) { bestv[r] = 3.4e38f; bestc[r] = 0; }

    // two named register sets (static indexing — no dynamic array idx)
    float fa0[4], fa1[4];
    uint4 u00, u01, u10, u11;
    float fb0[16], fb1[16];

    // ---- helpers ----
    auto issueA = [&](int c, float (&fa)[4]) {
        const int dt = (c & 7) * CD;
        fa[0] = xA[(size_t)(dt + 0) * SS];
        fa[1] = xA[(size_t)(dt + 1) * SS];
        fa[2] = xA[(size_t)(dt + 16) * SS];
        fa[3] = xA[(size_t)(dt + 17) * SS];
    };
    auto issueB = [&](int c, uint4& a0, uint4& a1, float (&fb)[16]) {
        const int kt = c >> 3;
        const int dt = (c & 7) * CD;
        if constexpr (PRE) {
            const int qg = (dt >> 3) + 2 * oB;
            const size_t kb = (size_t)kt * NTT + cod_b;
            a0 = epk[(size_t)(qg * 2 + pB) * KK + kb];
            a1 = epk[(size_t)((qg + 1) * 2 + pB) * KK + kb];
        } else {
#pragma unroll
            for (int i = 0; i < 16; ++i)
                fb[i] = emb[(size_t)(dt + oB * 16 + i) * KK
                            + (size_t)kt * NTT + cod_b];
        }
    };
    auto stageWrite = [&](int nxt, float (&fa)[4], uint4& a0, uint4& a1,
                          float (&fb)[16]) {
        ushort h0, l0, h1, l1, h2, l2, h3, l3;
        split16(fa[0], h0, l0); split16(fa[1], h1, l1);
        split16(fa[2], h2, l2); split16(fa[3], h3, l3);
        *reinterpret_cast<uint*>(&Ah[nxt][lat_a * LDA + 2 * d2a]) = pk(h0, h1);
        *reinterpret_cast<uint*>(&Al[nxt][lat_a * LDA + 2 * d2a]) = pk(l0, l1);
        *reinterpret_cast<uint*>(&Ah[nxt][lat_a * LDA + 2 * d2a + 16]) = pk(h2, h3);
        *reinterpret_cast<uint*>(&Al[nxt][lat_a * LDA + 2 * d2a + 16]) = pk(l2, l3);
        uint4 w0, w1;
        if constexpr (PRE) {
            w0 = a0; w1 = a1;
        } else {
            ushort hh[16], ll[16];
#pragma unroll
            for (int i = 0; i < 16; ++i) split16(fb[i], hh[i], ll[i]);
            const ushort* s = pB ? ll : hh;
            w0.x = pk(s[0], s[1]);   w0.y = pk(s[2], s[3]);
            w0.z = pk(s[4], s[5]);   w0.w = pk(s[6], s[7]);
            w1.x = pk(s[8], s[9]);   w1.y = pk(s[10], s[11]);
            w1.z = pk(s[12], s[13]); w1.w = pk(s[14], s[15]);
        }
        ushort* Bp = pB ? &Bl[nxt][0] : &Bh[nxt][0];
        *reinterpret_cast<uint4*>(&Bp[cod_b * LDA + oB * 16]) = w0;
        *reinterpret_cast<uint4*>(&Bp[cod_b * LDA + oB * 16 + 8]) = w1;
    };
    auto compute = [&](int cur) {
        const int fo = colk * LDA + half * 8;
#pragma unroll
        for (int t = 0; t < 2; ++t) {
            const int o = t * 16;
            half8v ah = *reinterpret_cast<const half8v*>(&Ah[cur][fo + wm * LDA + o]);
            half8v al = *reinterpret_cast<const half8v*>(&Al[cur][fo + wm * LDA + o]);
            half8v bh0 = *reinterpret_cast<const half8v*>(&Bh[cur][fo + wn * LDA + o]);
            half8v bh1 = *reinterpret_cast<const half8v*>(&Bh[cur][fo + (wn + 32) * LDA + o]);
            half8v bl0 = *reinterpret_cast<const half8v*>(&Bl[cur][fo + wn * LDA + o]);
            half8v bl1 = *reinterpret_cast<const half8v*>(&Bl[cur][fo + (wn + 32) * LDA + o]);

            acc[0] = MFMA_F16(ah, bh0, acc[0], 0, 0, 0);
            acc[0] = MFMA_F16(ah, bl0, acc[0], 0, 0, 0);
            acc[0] = MFMA_F16(al, bh0, acc[0], 0, 0, 0);

            acc[1] = MFMA_F16(ah, bh1, acc[1], 0, 0, 0);
            acc[1] = MFMA_F16(ah, bl1, acc[1], 0, 0, 0);
            acc[1] = MFMA_F16(al, bh1, acc[1], 0, 0, 0);
        }
    };
    auto epilogue = [&](int kt) {
        const int cd0 = kt * NTT + wn + colk;
        const int cd1 = cd0 + 32;
        const float h0 = hn[cd0];
        const float h1 = hn[cd1];
#pragma unroll
        for (int r = 0; r < 16; ++r) {
            float s0 = h0 - acc[0][r];
            float s1 = h1 - acc[1][r];
            float v = s0; int cd = cd0;
            if (s1 < s0) { v = s1; cd = cd1; }   // strict <: smaller code wins ties
            if (v < bestv[r]) { bestv[r] = v; bestc[r] = cd; }
            acc[0][r] = 0.f;
            acc[1][r] = 0.f;
        }
    };

    // ---- prologue: stage chunk 0, issue chunk 1 ----
    issueA(0, fa0); issueB(0, u00, u01, fb0);
    stageWrite(0, fa0, u00, u01, fb0);           // one exposed vmcnt wait
    issueA(1, fa1); issueB(1, u10, u11, fb1);    // stays in flight over barrier
    __syncthreads();

    // ---- main loop: 64 chunks (8 kt x 8 dt of K-depth 32), 2 per iter ----
    for (int cc = 0; cc < 32; ++cc) {
        const int c0 = cc * 2;
        // even step: cur=0, nxt=1; set0 free (data c0 already in LDS)
        if (c0 + 2 < 64) { issueA(c0 + 2, fa0); issueB(c0 + 2, u00, u01, fb0); }
        stageWrite(1, fa1, u10, u11, fb1);       // data(c0+1): issued 1 chunk ago
        compute(0);
        __syncthreads();

        // odd step: cur=1, nxt=0; set1 free
        const int c1 = c0 + 1;
        if (c1 + 2 < 64) { issueA(c1 + 2, fa1); issueB(c1 + 2, u10, u11, fb1); }
        if (c1 + 1 < 64) { stageWrite(0, fa0, u00, u01, fb0); }
        compute(1);
        if ((c1 & 7) == 7) epilogue(c1 >> 3);
        __syncthreads();
    }

    // ---- cross-lane argmin: butterfly over the 32 colk lanes ----
#pragma unroll
    for (int r = 0; r < 16; ++r) {
        float v = bestv[r];
        int cd = bestc[r];
#pragma unroll
        for (int mk = 1; mk < 32; mk <<= 1) {
            float ov = __shfl_xor(v, mk);
            int oc = __shfl_xor(cd, mk);
            if (ov < v || (ov == v && oc < cd)) { v = ov; cd = oc; }
        }
        if (colk == 0) {
            const int row = (r & 3) + 8 * (r >> 2) + 4 * half;  // verified C/D map
            sv[wid >> 2][wm + row] = v;
            sc[wid >> 2][wm + row] = cd;
        }
    }
    __syncthreads();
    // ---- combine the 4 n-wave groups ----
    if (tid < MT) {
        float v = sv[0][tid]; int cd = sc[0][tid];
#pragma unroll
        for (int g = 1; g < 4; ++g) {
            float ov = sv[g][tid]; int oc = sc[g][tid];
            if (ov < v || (ov == v && oc < cd)) { v = ov; cd = oc; }
        }
        bc[tid] = cd;
    }
    __syncthreads();
    // ---- fused gather: out[(bq*DD+d)*SS + sb + m] = emb[d*KK + bc[m]] ----
    {
        const int mq = tid & 31;     // float4 group along m (128 cols = 32 groups)
        const int dg = tid >> 5;     // 0..31, 8 d's each
        const int k0 = bc[mq * 4 + 0];
        const int k1 = bc[mq * 4 + 1];
        const int k2 = bc[mq * 4 + 2];
        const int k3 = bc[mq * 4 + 3];
#pragma unroll 4
        for (int dd = 0; dd < 8; ++dd) {
            const int d = dg * 8 + dd;
            const float* er = emb + (size_t)d * KK;
            float4 o = make_float4(er[k0], er[k1], er[k2], er[k3]);
            reinterpret_cast<float4*>(&out[((size_t)bq * DD + d) * SS + sb])[mq] = o;
        }
    }
}

extern "C" void kernel_launch(void* const* d_in, const int* in_sizes, int n_in,
                              void* d_out, int out_size, void* d_ws, size_t ws_size,
                              hipStream_t stream) {
    const float* x = (const float*)d_in[0];     // (32,256,32,32)
    const float* emb = (const float*)d_in[1];   // (256,2048)
    float* out = (float*)d_out;
    float* hn = (float*)d_ws;                   // 2048 f32 = 8 KB (proven safe)
    uint4* epk = (uint4*)((char*)d_ws + KK * sizeof(float));  // 2 MB packed emb

    // 32 quads * 2 planes * 2048 codes * 16 B = 2 MB
    const size_t need = (size_t)KK * 4 + (size_t)32 * 2 * KK * 16;

    hipLaunchKernelGGL(hn_kernel, dim3(KK / 32), dim3(256), 0, stream, emb, hn);
    if (ws_size >= need) {
        hipLaunchKernelGGL(pack_emb, dim3(65536 / 256), dim3(256), 0, stream,
                           emb, epk);
        hipLaunchKernelGGL((vq_fused<true>), dim3(NN / MT), dim3(1024), 0, stream,
                           x, emb, hn, epk, out);
    } else {
        hipLaunchKernelGGL((vq_fused<false>), dim3(NN / MT), dim3(1024), 0, stream,
                           x, emb, hn, epk, out);
    }
}